// Round 1
// baseline (3940.726 us; speedup 1.0000x reference)
//
#include <hip/hip_runtime.h>

#define EPS 1e-5f

// ---------------------------------------------------------------------------
// scatter_gemm: for each row r in [0, K*P): k = r/P, gather x[in_idx[r]],
// compute (x_row · W[k][:, o]) for each o, atomicAdd into out[out_idx[r]].
// Block = 256 threads; each group of COUT threads handles one row.
// ---------------------------------------------------------------------------
template <int CIN, int COUT>
__global__ __launch_bounds__(256) void scatter_gemm(
    const float* __restrict__ x, const float* __restrict__ W,
    const int* __restrict__ in_idx, const int* __restrict__ out_idx,
    float* __restrict__ out, int total_rows, int P)
{
    const int ROWS_PER_BLOCK = 256 / COUT;
    int r = blockIdx.x * ROWS_PER_BLOCK + threadIdx.x / COUT;
    if (r >= total_rows) return;
    int o = threadIdx.x % COUT;
    int k = r / P;
    int in  = in_idx[r];
    int orow = out_idx[r];
    const float* xr = x + (size_t)in * CIN;
    const float* Wk = W + (size_t)k * CIN * COUT + o;
    float acc = 0.f;
#pragma unroll 8
    for (int i = 0; i < CIN; ++i) {
        acc = fmaf(xr[i], Wk[(size_t)i * COUT], acc);
    }
    atomicAdd(&out[(size_t)orow * COUT + o], acc);
}

// ---------------------------------------------------------------------------
// reduce_stats: per-channel sum and sum-of-squares over n_rows rows.
// stats[0..COUT) = sum, stats[COUT..2*COUT) = sumsq. Must be pre-zeroed.
// ---------------------------------------------------------------------------
template <int COUT>
__global__ __launch_bounds__(256) void reduce_stats(
    const float* __restrict__ out, float* __restrict__ stats, int n_rows)
{
    const int RPP = 256 / COUT;  // rows per pass per block
    int c = threadIdx.x % COUT;
    int g = threadIdx.x / COUT;
    float s = 0.f, ss = 0.f;
    for (long long row = (long long)blockIdx.x * RPP + g; row < n_rows;
         row += (long long)gridDim.x * RPP) {
        float v = out[row * COUT + c];
        s += v;
        ss += v * v;
    }
    __shared__ float sh_s[256];
    __shared__ float sh_ss[256];
    sh_s[threadIdx.x] = s;
    sh_ss[threadIdx.x] = ss;
    __syncthreads();
    for (int off = 128; off >= COUT; off >>= 1) {
        if (threadIdx.x < off) {
            sh_s[threadIdx.x] += sh_s[threadIdx.x + off];
            sh_ss[threadIdx.x] += sh_ss[threadIdx.x + off];
        }
        __syncthreads();
    }
    if (threadIdx.x < COUT) {
        atomicAdd(&stats[c], sh_s[c]);
        atomicAdd(&stats[COUT + c], sh_ss[c]);
    }
}

// ---------------------------------------------------------------------------
// bn_skip: y = (v - mean) * rsqrt(var + eps) * gamma + beta + skip, in place.
// Processes float4 (4 consecutive channels) per thread.
// ---------------------------------------------------------------------------
template <int COUT>
__global__ __launch_bounds__(256) void bn_skip(
    float* __restrict__ out, const float* __restrict__ skip,
    const float* __restrict__ gamma, const float* __restrict__ beta,
    const float* __restrict__ stats, int n_rows)
{
    const int C4 = COUT / 4;
    long long idx = (long long)blockIdx.x * blockDim.x + threadIdx.x;
    long long total = (long long)n_rows * C4;
    if (idx >= total) return;
    int c4 = (int)(idx % C4);
    float4 v = ((const float4*)out)[idx];
    float4 sk = ((const float4*)skip)[idx];
    float inv_n = 1.f / (float)n_rows;
    float r[4] = {v.x, v.y, v.z, v.w};
    float skv[4] = {sk.x, sk.y, sk.z, sk.w};
#pragma unroll
    for (int j = 0; j < 4; ++j) {
        int c = c4 * 4 + j;
        float mean = stats[c] * inv_n;
        float var = stats[COUT + c] * inv_n - mean * mean;
        float scale = rsqrtf(var + EPS) * gamma[c];
        r[j] = (r[j] - mean) * scale + beta[c] + skv[j];
    }
    float4 res = {r[0], r[1], r[2], r[3]};
    ((float4*)out)[idx] = res;
}

extern "C" void kernel_launch(void* const* d_in, const int* in_sizes, int n_in,
                              void* d_out, int out_size, void* d_ws, size_t ws_size,
                              hipStream_t stream) {
    const float* x3    = (const float*)d_in[0];
    const float* skip3 = (const float*)d_in[1];
    const float* skip2 = (const float*)d_in[2];
    const float* skip1 = (const float*)d_in[3];
    const float* W3    = (const float*)d_in[4];
    const float* W2    = (const float*)d_in[5];
    const float* W1    = (const float*)d_in[6];
    const float* gamma3 = (const float*)d_in[7];
    const float* beta3  = (const float*)d_in[8];
    const float* gamma2 = (const float*)d_in[9];
    const float* beta2  = (const float*)d_in[10];
    const float* gamma1 = (const float*)d_in[11];
    const float* beta1  = (const float*)d_in[12];
    const int* in_idx3  = (const int*)d_in[13];
    const int* out_idx3 = (const int*)d_in[14];
    const int* in_idx2  = (const int*)d_in[15];
    const int* out_idx2 = (const int*)d_in[16];
    const int* in_idx1  = (const int*)d_in[17];
    const int* out_idx1 = (const int*)d_in[18];

    const int N3 = 40000, N2 = 160000, N1 = 640000, N0 = 2560000;
    const int K = 9;

    float* buf3  = (float*)d_ws;                    // N2 * 64
    float* buf2  = buf3 + (size_t)N2 * 64;          // N1 * 32
    float* stats = buf2 + (size_t)N1 * 32;          // 128 floats

    float* outp = (float*)d_out;                    // N0 * 32

    // ---------------- Level 3: x3[N3,128] -> buf3[N2,64] ----------------
    hipMemsetAsync(buf3, 0, (size_t)N2 * 64 * sizeof(float), stream);
    hipMemsetAsync(stats, 0, 128 * sizeof(float), stream);
    {
        int rows = K * N3;
        int rpb = 256 / 64;
        scatter_gemm<128, 64><<<(rows + rpb - 1) / rpb, 256, 0, stream>>>(
            x3, W3, in_idx3, out_idx3, buf3, rows, N3);
    }
    reduce_stats<64><<<1024, 256, 0, stream>>>(buf3, stats, N2);
    {
        long long tot = (long long)N2 * (64 / 4);
        bn_skip<64><<<(int)((tot + 255) / 256), 256, 0, stream>>>(
            buf3, skip3, gamma3, beta3, stats, N2);
    }

    // ---------------- Level 2: buf3[N2,64] -> buf2[N1,32] ----------------
    hipMemsetAsync(buf2, 0, (size_t)N1 * 32 * sizeof(float), stream);
    hipMemsetAsync(stats, 0, 128 * sizeof(float), stream);
    {
        int rows = K * N2;
        int rpb = 256 / 32;
        scatter_gemm<64, 32><<<(rows + rpb - 1) / rpb, 256, 0, stream>>>(
            buf3, W2, in_idx2, out_idx2, buf2, rows, N2);
    }
    reduce_stats<32><<<2048, 256, 0, stream>>>(buf2, stats, N1);
    {
        long long tot = (long long)N1 * (32 / 4);
        bn_skip<32><<<(int)((tot + 255) / 256), 256, 0, stream>>>(
            buf2, skip2, gamma2, beta2, stats, N1);
    }

    // ---------------- Level 1: buf2[N1,32] -> d_out[N0,32] ----------------
    hipMemsetAsync(outp, 0, (size_t)N0 * 32 * sizeof(float), stream);
    hipMemsetAsync(stats, 0, 128 * sizeof(float), stream);
    {
        int rows = K * N1;
        int rpb = 256 / 32;
        scatter_gemm<32, 32><<<(rows + rpb - 1) / rpb, 256, 0, stream>>>(
            buf2, W1, in_idx1, out_idx1, outp, rows, N1);
    }
    reduce_stats<32><<<4096, 256, 0, stream>>>(outp, stats, N0);
    {
        long long tot = (long long)N0 * (32 / 4);
        bn_skip<32><<<(int)((tot + 255) / 256), 256, 0, stream>>>(
            outp, skip1, gamma1, beta1, stats, N0);
    }
}